// Round 17
// baseline (300.058 us; speedup 1.0000x reference)
//
#include <hip/hip_runtime.h>
#include <hip/hip_bf16.h>
#include <cstdint>

// LSTM cell: B=8192, D=1024, U=1024.
// Round 17 = R8 best-known kernel (real output) + DIAGNOSTIC skeleton dispatch:
// identical window structure with MFMAs removed (frags kept live via asm sinks),
// loop doubled so it shows in top-5. Skeleton does zero stores.

using f32x4  = __attribute__((ext_vector_type(4))) float;
using short8 = __attribute__((ext_vector_type(8))) short;

__device__ __forceinline__ unsigned short f2bf(float f) {
  union { float f; unsigned int u; } v; v.f = f;
  unsigned int r = v.u + 0x7fffu + ((v.u >> 16) & 1u);  // RNE
  return (unsigned short)(r >> 16);
}
__device__ __forceinline__ float sigmoidf_fast(float x) { return 1.f / (1.f + __expf(-x)); }
__device__ __forceinline__ float tanhf_fast(float x)    { return 1.f - 2.f / (__expf(2.f * x) + 1.f); }

// ---------- A conversion: Abf[b][k] = bf16(k<1024 ? X[b][k] : H[b][k-1024])
__global__ void conv_a_kernel(const float* __restrict__ X, const float* __restrict__ H,
                              unsigned short* __restrict__ Abf) {
  int idx = blockIdx.x * blockDim.x + threadIdx.x;
  int b  = idx >> 8;
  int kq = (idx & 255) << 2;
  float4 x = *(const float4*)(X + (long)b * 1024 + kq);
  float4 h = *(const float4*)(H + (long)b * 1024 + kq);
  ushort4 xo, ho;
  xo.x = f2bf(x.x); xo.y = f2bf(x.y); xo.z = f2bf(x.z); xo.w = f2bf(x.w);
  ho.x = f2bf(h.x); ho.y = f2bf(h.y); ho.z = f2bf(h.z); ho.w = f2bf(h.w);
  *(ushort4*)(Abf + (long)b * 2048 + kq)        = xo;
  *(ushort4*)(Abf + (long)b * 2048 + 1024 + kq) = ho;
}

// ---------- B conversion: Bt[n][k] bf16, N-major, n = (u>>4)*64 + g*16 + (u&15)
__global__ void conv_b_kernel(const float* W_i, const float* U_i,
                              const float* W_f, const float* U_f,
                              const float* W_c, const float* U_c,
                              const float* W_o, const float* U_o,
                              unsigned short* __restrict__ Bt) {
  __shared__ float tile[64][65];
  int z = blockIdx.z;
  const float* src;
  switch (z) {
    case 0: src = W_i; break; case 1: src = U_i; break;
    case 2: src = W_f; break; case 3: src = U_f; break;
    case 4: src = W_c; break; case 5: src = U_c; break;
    case 6: src = W_o; break; default: src = U_o; break;
  }
  int g = z >> 1, s = z & 1;
  int k0 = blockIdx.x * 64;
  int u0 = blockIdx.y * 64;
  int t = threadIdx.x;
  int c = t & 63, r0 = t >> 6;
#pragma unroll
  for (int i = 0; i < 16; ++i) {
    int r = i * 4 + r0;
    tile[r][c] = src[(long)(k0 + r) * 1024 + u0 + c];
  }
  __syncthreads();
  int ul = t >> 2;
  int ks = (t & 3) * 16;
  unsigned short outv[16];
#pragma unroll
  for (int j = 0; j < 16; ++j) outv[j] = f2bf(tile[ks + j][ul]);
  long n   = 4L * u0 + (ul >> 4) * 64 + g * 16 + (ul & 15);
  long col = (long)s * 1024 + k0 + ks;
  uint4* dst = (uint4*)(Bt + n * 2048 + col);
  dst[0] = *(uint4*)(outv);
  dst[1] = *(uint4*)(outv + 8);
}

// ---------- fused GEMM + LSTM epilogue (R8 verbatim: best known, 143us)
__global__ __launch_bounds__(512, 2) void lstm_gemm_kernel(
    const unsigned short* __restrict__ Abf,
    const unsigned short* __restrict__ Btbf,
    const float* __restrict__ b_i, const float* __restrict__ b_f,
    const float* __restrict__ b_c, const float* __restrict__ b_o,
    const float* __restrict__ c_tm1,
    float* __restrict__ outH, float* __restrict__ outC) {
  __shared__ unsigned short smem[49152];  // 96KB

  int bid = blockIdx.x;
  int swz = (bid & 7) * 64 + (bid >> 3);
  int bm = swz >> 4;
  int bn = swz & 15;

  int t = threadIdx.x;
  int lane = t & 63;
  int w = t >> 6;
  int wm = w >> 2;
  int wn = w & 3;
  int rl = lane & 15;
  int kg = lane >> 4;

#define AOFFE(MI) ((wm * 128 + (MI) * 16 + rl) * 32 + \
    ((kg ^ (((wm * 128 + (MI) * 16 + rl) >> 1) & 3)) << 3))
#define BOFFE(NI) (8192 + (wn * 64 + (NI) * 16 + rl) * 32 + \
    ((kg ^ (((wn * 64 + (NI) * 16 + rl) >> 1) & 3)) << 3))
  const int offA0 = AOFFE(0), offA1 = AOFFE(1), offA2 = AOFFE(2), offA3 = AOFFE(3);
  const int offA4 = AOFFE(4), offA5 = AOFFE(5), offA6 = AOFFE(6), offA7 = AOFFE(7);
  const int offB0 = BOFFE(0), offB1 = BOFFE(1), offB2 = BOFFE(2), offB3 = BOFFE(3);
#undef AOFFE
#undef BOFFE

  int srow = t >> 2;
  int cbe  = (((t & 3) ^ ((srow >> 1) & 3))) << 3;
  const unsigned short* aS0 = Abf  + (long)(bm * 256 + srow) * 2048 + cbe;
  const unsigned short* aS1 = aS0 + 128L * 2048;
  const unsigned short* bS0 = Btbf + (long)(bn * 256 + srow) * 2048 + cbe;
  const unsigned short* bS1 = bS0 + 128L * 2048;
  const int dA = t * 8;

#define GLL(SRC, DELM)                                                                     \
  __builtin_amdgcn_global_load_lds((const __attribute__((address_space(1))) void*)(SRC),   \
      (__attribute__((address_space(3))) void*)(&smem[DELM]), 16, 0, 0)
#define VMC(N) asm volatile("s_waitcnt vmcnt(" #N ")" ::: "memory")

  f32x4 acc[8][4];
#pragma unroll
  for (int mi = 0; mi < 8; ++mi)
#pragma unroll
    for (int ni = 0; ni < 4; ++ni) acc[mi][ni] = (f32x4){0.f, 0.f, 0.f, 0.f};

  short8 aw0, aw1, aw2, aw3, bb0, bb1, bb2, bb3;

#define MF4(AF, MI)                                                                      \
  acc[MI][0] = __builtin_amdgcn_mfma_f32_16x16x32_bf16(AF, bb0, acc[MI][0], 0, 0, 0);    \
  acc[MI][1] = __builtin_amdgcn_mfma_f32_16x16x32_bf16(AF, bb1, acc[MI][1], 0, 0, 0);    \
  acc[MI][2] = __builtin_amdgcn_mfma_f32_16x16x32_bf16(AF, bb2, acc[MI][2], 0, 0, 0);    \
  acc[MI][3] = __builtin_amdgcn_mfma_f32_16x16x32_bf16(AF, bb3, acc[MI][3], 0, 0, 0);

#define WINDOW(RB, SB, KOFF, DOSTAGE, VMN, DOBAR)                              \
  {                                                                            \
    const unsigned short* Ab_ = smem + (RB) * 16384;                           \
    bb0 = *(const short8*)(Ab_ + offB0);                                       \
    bb1 = *(const short8*)(Ab_ + offB1);                                       \
    bb2 = *(const short8*)(Ab_ + offB2);                                       \
    bb3 = *(const short8*)(Ab_ + offB3);                                       \
    aw0 = *(const short8*)(Ab_ + offA0);                                       \
    aw1 = *(const short8*)(Ab_ + offA1);                                       \
    aw2 = *(const short8*)(Ab_ + offA2);                                       \
    aw3 = *(const short8*)(Ab_ + offA3);                                       \
    if (DOSTAGE) {                                                             \
      GLL(aS0 + (KOFF), (SB) * 16384 + dA);                                    \
      GLL(aS1 + (KOFF), (SB) * 16384 + 4096 + dA);                             \
    }                                                                          \
    __builtin_amdgcn_s_setprio(1);                                             \
    MF4(aw0, 0) MF4(aw1, 1) MF4(aw2, 2) MF4(aw3, 3)                            \
    __builtin_amdgcn_s_setprio(0);                                             \
    aw0 = *(const short8*)(Ab_ + offA4);                                       \
    aw1 = *(const short8*)(Ab_ + offA5);                                       \
    aw2 = *(const short8*)(Ab_ + offA6);                                       \
    aw3 = *(const short8*)(Ab_ + offA7);                                       \
    if (DOSTAGE) {                                                             \
      GLL(bS0 + (KOFF), (SB) * 16384 + 8192 + dA);                             \
      GLL(bS1 + (KOFF), (SB) * 16384 + 12288 + dA);                            \
    }                                                                          \
    __builtin_amdgcn_s_setprio(1);                                             \
    MF4(aw0, 4) MF4(aw1, 5) MF4(aw2, 6) MF4(aw3, 7)                            \
    __builtin_amdgcn_s_setprio(0);                                             \
    if ((VMN) == 4) VMC(4);                                                    \
    if ((VMN) == 0) VMC(0);                                                    \
    if (DOBAR) __builtin_amdgcn_s_barrier();                                   \
  }

  GLL(aS0, dA);            GLL(aS1, 4096 + dA);
  GLL(bS0, 8192 + dA);     GLL(bS1, 12288 + dA);
  GLL(aS0 + 32, 16384 + dA);        GLL(aS1 + 32, 16384 + 4096 + dA);
  GLL(bS0 + 32, 16384 + 8192 + dA); GLL(bS1 + 32, 16384 + 12288 + dA);
  VMC(4);
  __builtin_amdgcn_s_barrier();
  aS0 += 64; aS1 += 64; bS0 += 64; bS1 += 64;

  for (int g = 0; g < 20; ++g) {
    WINDOW(0, 2, 0,  1, 4, 1);
    WINDOW(1, 0, 32, 1, 4, 1);
    WINDOW(2, 1, 64, 1, 4, 1);
    aS0 += 96; aS1 += 96; bS0 += 96; bS1 += 96;
  }
  WINDOW(0, 2, 0,  1, 4, 1);
  WINDOW(1, 0, 32, 1, 4, 1);
  WINDOW(2, 0, 0,  0, 0, 1);
  WINDOW(0, 0, 0,  0, -1, 0);
#undef WINDOW
#undef MF4
#undef VMC
#undef GLL

  int mbase = bm * 256 + wm * 128;
  int nbase = bn * 256 + wn * 64;
  int u = (nbase >> 2) + rl;
  float bi_v = b_i[u], bf_v = b_f[u], bc_v = b_c[u], bo_v = b_o[u];
  int rquad = (lane >> 4) << 2;
#pragma unroll
  for (int mi = 0; mi < 8; ++mi) {
#pragma unroll
    for (int j = 0; j < 4; ++j) {
      int brow = mbase + mi * 16 + rquad + j;
      float zi = acc[mi][0][j] + bi_v;
      float zf = acc[mi][1][j] + bf_v;
      float zc = acc[mi][2][j] + bc_v;
      float zo = acc[mi][3][j] + bo_v;
      float ig = sigmoidf_fast(zi);
      float fg = sigmoidf_fast(zf);
      float cg = tanhf_fast(zc);
      float og = sigmoidf_fast(zo);
      float cp = c_tm1[(long)brow * 1024 + u];
      float cn = fg * cp + ig * cg;
      float hn = og * tanhf_fast(cn);
      outH[(long)brow * 1024 + u] = hn;
      outC[(long)brow * 1024 + u] = cn;
    }
  }
}

// ---------- DIAGNOSTIC skeleton: R8 structure, MFMAs removed, loads kept live.
// Runs the 64-window loop TWICE (appears in top-5). Zero stores.
__global__ __launch_bounds__(512, 2) void gemm_skeleton_x2(
    const unsigned short* __restrict__ Abf,
    const unsigned short* __restrict__ Btbf) {
  __shared__ unsigned short smem[49152];

  int bid = blockIdx.x;
  int swz = (bid & 7) * 64 + (bid >> 3);
  int bm = swz >> 4;
  int bn = swz & 15;

  int t = threadIdx.x;
  int lane = t & 63;
  int w = t >> 6;
  int wm = w >> 2;
  int wn = w & 3;
  int rl = lane & 15;
  int kg = lane >> 4;

#define AOFFE(MI) ((wm * 128 + (MI) * 16 + rl) * 32 + \
    ((kg ^ (((wm * 128 + (MI) * 16 + rl) >> 1) & 3)) << 3))
#define BOFFE(NI) (8192 + (wn * 64 + (NI) * 16 + rl) * 32 + \
    ((kg ^ (((wn * 64 + (NI) * 16 + rl) >> 1) & 3)) << 3))
  const int offA0 = AOFFE(0), offA1 = AOFFE(1), offA2 = AOFFE(2), offA3 = AOFFE(3);
  const int offA4 = AOFFE(4), offA5 = AOFFE(5), offA6 = AOFFE(6), offA7 = AOFFE(7);
  const int offB0 = BOFFE(0), offB1 = BOFFE(1), offB2 = BOFFE(2), offB3 = BOFFE(3);
#undef AOFFE
#undef BOFFE

  int srow = t >> 2;
  int cbe  = (((t & 3) ^ ((srow >> 1) & 3))) << 3;
  const int dA = t * 8;

#define GLL(SRC, DELM)                                                                     \
  __builtin_amdgcn_global_load_lds((const __attribute__((address_space(1))) void*)(SRC),   \
      (__attribute__((address_space(3))) void*)(&smem[DELM]), 16, 0, 0)
#define VMC(N) asm volatile("s_waitcnt vmcnt(" #N ")" ::: "memory")
#define SINK(V) asm volatile("" :: "v"(V))

  short8 aw0, aw1, aw2, aw3, bb0, bb1, bb2, bb3;

#define SWIN(RB, SB, KOFF, DOSTAGE, VMN, DOBAR)                                \
  {                                                                            \
    const unsigned short* Ab_ = smem + (RB) * 16384;                           \
    bb0 = *(const short8*)(Ab_ + offB0);                                       \
    bb1 = *(const short8*)(Ab_ + offB1);                                       \
    bb2 = *(const short8*)(Ab_ + offB2);                                       \
    bb3 = *(const short8*)(Ab_ + offB3);                                       \
    aw0 = *(const short8*)(Ab_ + offA0);                                       \
    aw1 = *(const short8*)(Ab_ + offA1);                                       \
    aw2 = *(const short8*)(Ab_ + offA2);                                       \
    aw3 = *(const short8*)(Ab_ + offA3);                                       \
    if (DOSTAGE) {                                                             \
      GLL(aS0 + (KOFF), (SB) * 16384 + dA);                                    \
      GLL(aS1 + (KOFF), (SB) * 16384 + 4096 + dA);                             \
    }                                                                          \
    SINK(bb0); SINK(bb1); SINK(bb2); SINK(bb3);                                \
    SINK(aw0); SINK(aw1); SINK(aw2); SINK(aw3);                                \
    aw0 = *(const short8*)(Ab_ + offA4);                                       \
    aw1 = *(const short8*)(Ab_ + offA5);                                       \
    aw2 = *(const short8*)(Ab_ + offA6);                                       \
    aw3 = *(const short8*)(Ab_ + offA7);                                       \
    if (DOSTAGE) {                                                             \
      GLL(bS0 + (KOFF), (SB) * 16384 + 8192 + dA);                             \
      GLL(bS1 + (KOFF), (SB) * 16384 + 12288 + dA);                            \
    }                                                                          \
    SINK(aw0); SINK(aw1); SINK(aw2); SINK(aw3);                                \
    if ((VMN) == 4) VMC(4);                                                    \
    if ((VMN) == 0) VMC(0);                                                    \
    if (DOBAR) __builtin_amdgcn_s_barrier();                                   \
  }

  for (int rep = 0; rep < 2; ++rep) {
    const unsigned short* aS0 = Abf  + (long)(bm * 256 + srow) * 2048 + cbe;
    const unsigned short* aS1 = aS0 + 128L * 2048;
    const unsigned short* bS0 = Btbf + (long)(bn * 256 + srow) * 2048 + cbe;
    const unsigned short* bS1 = bS0 + 128L * 2048;

    GLL(aS0, dA);            GLL(aS1, 4096 + dA);
    GLL(bS0, 8192 + dA);     GLL(bS1, 12288 + dA);
    GLL(aS0 + 32, 16384 + dA);        GLL(aS1 + 32, 16384 + 4096 + dA);
    GLL(bS0 + 32, 16384 + 8192 + dA); GLL(bS1 + 32, 16384 + 12288 + dA);
    VMC(4);
    __builtin_amdgcn_s_barrier();
    aS0 += 64; aS1 += 64; bS0 += 64; bS1 += 64;

    for (int g = 0; g < 20; ++g) {
      SWIN(0, 2, 0,  1, 4, 1);
      SWIN(1, 0, 32, 1, 4, 1);
      SWIN(2, 1, 64, 1, 4, 1);
      aS0 += 96; aS1 += 96; bS0 += 96; bS1 += 96;
    }
    SWIN(0, 2, 0,  1, 4, 1);
    SWIN(1, 0, 32, 1, 4, 1);
    SWIN(2, 0, 0,  0, 0, 1);
    SWIN(0, 0, 0,  0, -1, 0);
  }
#undef SWIN
#undef SINK
#undef VMC
#undef GLL
}

extern "C" void kernel_launch(void* const* d_in, const int* in_sizes, int n_in,
                              void* d_out, int out_size, void* d_ws, size_t ws_size,
                              hipStream_t stream) {
  (void)in_sizes; (void)n_in; (void)out_size; (void)ws_size;
  const float* X   = (const float*)d_in[0];
  const float* Hst = (const float*)d_in[1];
  const float* Cst = (const float*)d_in[2];
  const float* W_i = (const float*)d_in[3];
  const float* U_i = (const float*)d_in[4];
  const float* b_i = (const float*)d_in[5];
  const float* W_f = (const float*)d_in[6];
  const float* U_f = (const float*)d_in[7];
  const float* b_f = (const float*)d_in[8];
  const float* W_c = (const float*)d_in[9];
  const float* U_c = (const float*)d_in[10];
  const float* b_c = (const float*)d_in[11];
  const float* W_o = (const float*)d_in[12];
  const float* U_o = (const float*)d_in[13];
  const float* b_o = (const float*)d_in[14];

  unsigned short* Abf  = (unsigned short*)d_ws;                        // 32 MB
  unsigned short* Btbf = (unsigned short*)((char*)d_ws + 33554432);    // 16 MB

  float* outH = (float*)d_out;
  float* outC = outH + 8192L * 1024;

  conv_a_kernel<<<8192, 256, 0, stream>>>(X, Hst, Abf);
  conv_b_kernel<<<dim3(16, 16, 8), 256, 0, stream>>>(W_i, U_i, W_f, U_f, W_c, U_c, W_o, U_o, Btbf);
  lstm_gemm_kernel<<<512, 512, 0, stream>>>(Abf, Btbf, b_i, b_f, b_c, b_o, Cst, outH, outC);
  gemm_skeleton_x2<<<512, 512, 0, stream>>>(Abf, Btbf);
}

// Round 18
// 153.589 us; speedup vs baseline: 1.9536x; 1.9536x over previous
//
#include <hip/hip_runtime.h>
#include <hip/hip_bf16.h>
#include <cstdint>

// LSTM cell: B=8192, D=1024, U=1024.
// z = [X|H](8192x2048) @ Wcat(2048x4096), gate interleave 16 in N, fused epilogue.
// GEMM: R8 structure (256x256 tile, BK=32, 8 waves 2Mx4N, 3 LDS bufs, one
// vmcnt(4)+barrier per window) with ALL s_setprio REMOVED: the prio-1 MFMA
// cluster was starving co-resident waves' ds_read/GLL issue (m190 signature),
// serializing the LDS pipe against the MFMA pipe (R17 skeleton: 1481+1242=2793).

using f32x4  = __attribute__((ext_vector_type(4))) float;
using short8 = __attribute__((ext_vector_type(8))) short;

__device__ __forceinline__ unsigned short f2bf(float f) {
  union { float f; unsigned int u; } v; v.f = f;
  unsigned int r = v.u + 0x7fffu + ((v.u >> 16) & 1u);  // RNE
  return (unsigned short)(r >> 16);
}
__device__ __forceinline__ float sigmoidf_fast(float x) { return 1.f / (1.f + __expf(-x)); }
__device__ __forceinline__ float tanhf_fast(float x)    { return 1.f - 2.f / (__expf(2.f * x) + 1.f); }

// ---------- A conversion: Abf[b][k] = bf16(k<1024 ? X[b][k] : H[b][k-1024])
__global__ void conv_a_kernel(const float* __restrict__ X, const float* __restrict__ H,
                              unsigned short* __restrict__ Abf) {
  int idx = blockIdx.x * blockDim.x + threadIdx.x;
  int b  = idx >> 8;
  int kq = (idx & 255) << 2;
  float4 x = *(const float4*)(X + (long)b * 1024 + kq);
  float4 h = *(const float4*)(H + (long)b * 1024 + kq);
  ushort4 xo, ho;
  xo.x = f2bf(x.x); xo.y = f2bf(x.y); xo.z = f2bf(x.z); xo.w = f2bf(x.w);
  ho.x = f2bf(h.x); ho.y = f2bf(h.y); ho.z = f2bf(h.z); ho.w = f2bf(h.w);
  *(ushort4*)(Abf + (long)b * 2048 + kq)        = xo;
  *(ushort4*)(Abf + (long)b * 2048 + 1024 + kq) = ho;
}

// ---------- B conversion: Bt[n][k] bf16, N-major, n = (u>>4)*64 + g*16 + (u&15)
__global__ void conv_b_kernel(const float* W_i, const float* U_i,
                              const float* W_f, const float* U_f,
                              const float* W_c, const float* U_c,
                              const float* W_o, const float* U_o,
                              unsigned short* __restrict__ Bt) {
  __shared__ float tile[64][65];
  int z = blockIdx.z;
  const float* src;
  switch (z) {
    case 0: src = W_i; break; case 1: src = U_i; break;
    case 2: src = W_f; break; case 3: src = U_f; break;
    case 4: src = W_c; break; case 5: src = U_c; break;
    case 6: src = W_o; break; default: src = U_o; break;
  }
  int g = z >> 1, s = z & 1;
  int k0 = blockIdx.x * 64;
  int u0 = blockIdx.y * 64;
  int t = threadIdx.x;
  int c = t & 63, r0 = t >> 6;
#pragma unroll
  for (int i = 0; i < 16; ++i) {
    int r = i * 4 + r0;
    tile[r][c] = src[(long)(k0 + r) * 1024 + u0 + c];
  }
  __syncthreads();
  int ul = t >> 2;
  int ks = (t & 3) * 16;
  unsigned short outv[16];
#pragma unroll
  for (int j = 0; j < 16; ++j) outv[j] = f2bf(tile[ks + j][ul]);
  long n   = 4L * u0 + (ul >> 4) * 64 + g * 16 + (ul & 15);
  long col = (long)s * 1024 + k0 + ks;
  uint4* dst = (uint4*)(Bt + n * 2048 + col);
  dst[0] = *(uint4*)(outv);
  dst[1] = *(uint4*)(outv + 8);
}

// ---------- fused GEMM + LSTM epilogue
// LDS buf (16384 shorts = 32KB): A[256][32] at +0, B[256][32] at +8192. 3 bufs.
__global__ __launch_bounds__(512, 2) void lstm_gemm_kernel(
    const unsigned short* __restrict__ Abf,   // [8192][2048] bf16
    const unsigned short* __restrict__ Btbf,  // [4096][2048] bf16 (N-major)
    const float* __restrict__ b_i, const float* __restrict__ b_f,
    const float* __restrict__ b_c, const float* __restrict__ b_o,
    const float* __restrict__ c_tm1,
    float* __restrict__ outH, float* __restrict__ outC) {
  __shared__ unsigned short smem[49152];  // 96KB

  int bid = blockIdx.x;
  int swz = (bid & 7) * 64 + (bid >> 3);  // XCD swizzle, 512 % 8 == 0
  int bm = swz >> 4;   // 32 m-blocks
  int bn = swz & 15;   // 16 n-blocks

  int t = threadIdx.x;
  int lane = t & 63;
  int w = t >> 6;           // 8 waves
  int wm = w >> 2;          // 0..1
  int wn = w & 3;           // 0..3
  int rl = lane & 15;
  int kg = lane >> 4;       // 0..3, 8-elem k-chunk

  // ---- ds_read frag offsets within a buf (XOR chunk swizzle: c ^= (row>>1)&3) ----
#define AOFFE(MI) ((wm * 128 + (MI) * 16 + rl) * 32 + \
    ((kg ^ (((wm * 128 + (MI) * 16 + rl) >> 1) & 3)) << 3))
#define BOFFE(NI) (8192 + (wn * 64 + (NI) * 16 + rl) * 32 + \
    ((kg ^ (((wn * 64 + (NI) * 16 + rl) >> 1) & 3)) << 3))
  const int offA0 = AOFFE(0), offA1 = AOFFE(1), offA2 = AOFFE(2), offA3 = AOFFE(3);
  const int offA4 = AOFFE(4), offA5 = AOFFE(5), offA6 = AOFFE(6), offA7 = AOFFE(7);
  const int offB0 = BOFFE(0), offB1 = BOFFE(1), offB2 = BOFFE(2), offB3 = BOFFE(3);
#undef AOFFE
#undef BOFFE

  // ---- staging: linear LDS dest, inverse-swizzled global source ----
  int srow = t >> 2;                                  // 0..127 (+128 second GLL)
  int cbe  = (((t & 3) ^ ((srow >> 1) & 3))) << 3;    // source k-elem offset
  const unsigned short* aS0 = Abf  + (long)(bm * 256 + srow) * 2048 + cbe;
  const unsigned short* aS1 = aS0 + 128L * 2048;
  const unsigned short* bS0 = Btbf + (long)(bn * 256 + srow) * 2048 + cbe;
  const unsigned short* bS1 = bS0 + 128L * 2048;
  const int dA = t * 8;

#define GLL(SRC, DELM)                                                                     \
  __builtin_amdgcn_global_load_lds((const __attribute__((address_space(1))) void*)(SRC),   \
      (__attribute__((address_space(3))) void*)(&smem[DELM]), 16, 0, 0)
#define VMC(N) asm volatile("s_waitcnt vmcnt(" #N ")" ::: "memory")

  f32x4 acc[8][4];
#pragma unroll
  for (int mi = 0; mi < 8; ++mi)
#pragma unroll
    for (int ni = 0; ni < 4; ++ni) acc[mi][ni] = (f32x4){0.f, 0.f, 0.f, 0.f};

  short8 aw0, aw1, aw2, aw3, bb0, bb1, bb2, bb3;

#define MF4(AF, MI)                                                                      \
  acc[MI][0] = __builtin_amdgcn_mfma_f32_16x16x32_bf16(AF, bb0, acc[MI][0], 0, 0, 0);    \
  acc[MI][1] = __builtin_amdgcn_mfma_f32_16x16x32_bf16(AF, bb1, acc[MI][1], 0, 0, 0);    \
  acc[MI][2] = __builtin_amdgcn_mfma_f32_16x16x32_bf16(AF, bb2, acc[MI][2], 0, 0, 0);    \
  acc[MI][3] = __builtin_amdgcn_mfma_f32_16x16x32_bf16(AF, bb3, acc[MI][3], 0, 0, 0);

// One K-tile window: read buf RB, stage tile (into buf SB) at source offset KOFF,
// counted vmcnt + single barrier at end. NO setprio anywhere.
#define WINDOW(RB, SB, KOFF, DOSTAGE, VMN, DOBAR)                              \
  {                                                                            \
    const unsigned short* Ab_ = smem + (RB) * 16384;                           \
    bb0 = *(const short8*)(Ab_ + offB0);                                       \
    bb1 = *(const short8*)(Ab_ + offB1);                                       \
    bb2 = *(const short8*)(Ab_ + offB2);                                       \
    bb3 = *(const short8*)(Ab_ + offB3);                                       \
    aw0 = *(const short8*)(Ab_ + offA0);                                       \
    aw1 = *(const short8*)(Ab_ + offA1);                                       \
    aw2 = *(const short8*)(Ab_ + offA2);                                       \
    aw3 = *(const short8*)(Ab_ + offA3);                                       \
    if (DOSTAGE) {                                                             \
      GLL(aS0 + (KOFF), (SB) * 16384 + dA);                                    \
      GLL(aS1 + (KOFF), (SB) * 16384 + 4096 + dA);                             \
    }                                                                          \
    MF4(aw0, 0) MF4(aw1, 1) MF4(aw2, 2) MF4(aw3, 3)                            \
    aw0 = *(const short8*)(Ab_ + offA4);                                       \
    aw1 = *(const short8*)(Ab_ + offA5);                                       \
    aw2 = *(const short8*)(Ab_ + offA6);                                       \
    aw3 = *(const short8*)(Ab_ + offA7);                                       \
    if (DOSTAGE) {                                                             \
      GLL(bS0 + (KOFF), (SB) * 16384 + 8192 + dA);                             \
      GLL(bS1 + (KOFF), (SB) * 16384 + 12288 + dA);                            \
    }                                                                          \
    MF4(aw0, 4) MF4(aw1, 5) MF4(aw2, 6) MF4(aw3, 7)                            \
    if ((VMN) == 4) VMC(4);                                                    \
    if ((VMN) == 0) VMC(0);                                                    \
    if (DOBAR) __builtin_amdgcn_s_barrier();                                   \
  }

  // ---- prologue: stage tiles 0 -> buf0, 1 -> buf1; drain tile 0 only ----
  GLL(aS0, dA);            GLL(aS1, 4096 + dA);
  GLL(bS0, 8192 + dA);     GLL(bS1, 12288 + dA);
  GLL(aS0 + 32, 16384 + dA);        GLL(aS1 + 32, 16384 + 4096 + dA);
  GLL(bS0 + 32, 16384 + 8192 + dA); GLL(bS1 + 32, 16384 + 12288 + dA);
  VMC(4);
  __builtin_amdgcn_s_barrier();
  aS0 += 64; aS1 += 64; bS0 += 64; bS1 += 64;   // source base -> tile 2

  // ---- windows 0..59 (stage tiles 2..61) ----
  for (int g = 0; g < 20; ++g) {
    WINDOW(0, 2, 0,  1, 4, 1);
    WINDOW(1, 0, 32, 1, 4, 1);
    WINDOW(2, 1, 64, 1, 4, 1);
    aS0 += 96; aS1 += 96; bS0 += 96; bS1 += 96;
  }
  // ---- tail: w60 stages t62, w61 stages t63, w62 drains, w63 pure compute ----
  WINDOW(0, 2, 0,  1, 4, 1);
  WINDOW(1, 0, 32, 1, 4, 1);
  WINDOW(2, 0, 0,  0, 0, 1);
  WINDOW(0, 0, 0,  0, -1, 0);
#undef WINDOW
#undef MF4
#undef VMC
#undef GLL

  // ---- fused LSTM epilogue ----
  // Wave N-span = 64 cols = one u-block: u = nbase/4 + rl; gate = ni.
  int mbase = bm * 256 + wm * 128;
  int nbase = bn * 256 + wn * 64;
  int u = (nbase >> 2) + rl;
  float bi_v = b_i[u], bf_v = b_f[u], bc_v = b_c[u], bo_v = b_o[u];
  int rquad = (lane >> 4) << 2;
#pragma unroll
  for (int mi = 0; mi < 8; ++mi) {
#pragma unroll
    for (int j = 0; j < 4; ++j) {
      int brow = mbase + mi * 16 + rquad + j;
      float zi = acc[mi][0][j] + bi_v;
      float zf = acc[mi][1][j] + bf_v;
      float zc = acc[mi][2][j] + bc_v;
      float zo = acc[mi][3][j] + bo_v;
      float ig = sigmoidf_fast(zi);
      float fg = sigmoidf_fast(zf);
      float cg = tanhf_fast(zc);
      float og = sigmoidf_fast(zo);
      float cp = c_tm1[(long)brow * 1024 + u];
      float cn = fg * cp + ig * cg;
      float hn = og * tanhf_fast(cn);
      outH[(long)brow * 1024 + u] = hn;
      outC[(long)brow * 1024 + u] = cn;
    }
  }
}

extern "C" void kernel_launch(void* const* d_in, const int* in_sizes, int n_in,
                              void* d_out, int out_size, void* d_ws, size_t ws_size,
                              hipStream_t stream) {
  (void)in_sizes; (void)n_in; (void)out_size; (void)ws_size;
  const float* X   = (const float*)d_in[0];
  const float* Hst = (const float*)d_in[1];
  const float* Cst = (const float*)d_in[2];
  const float* W_i = (const float*)d_in[3];
  const float* U_i = (const float*)d_in[4];
  const float* b_i = (const float*)d_in[5];
  const float* W_f = (const float*)d_in[6];
  const float* U_f = (const float*)d_in[7];
  const float* b_f = (const float*)d_in[8];
  const float* W_c = (const float*)d_in[9];
  const float* U_c = (const float*)d_in[10];
  const float* b_c = (const float*)d_in[11];
  const float* W_o = (const float*)d_in[12];
  const float* U_o = (const float*)d_in[13];
  const float* b_o = (const float*)d_in[14];

  unsigned short* Abf  = (unsigned short*)d_ws;                        // 32 MB
  unsigned short* Btbf = (unsigned short*)((char*)d_ws + 33554432);    // 16 MB

  float* outH = (float*)d_out;
  float* outC = outH + 8192L * 1024;

  conv_a_kernel<<<8192, 256, 0, stream>>>(X, Hst, Abf);
  conv_b_kernel<<<dim3(16, 16, 8), 256, 0, stream>>>(W_i, U_i, W_f, U_f, W_c, U_c, W_o, U_o, Btbf);
  lstm_gemm_kernel<<<512, 512, 0, stream>>>(Abf, Btbf, b_i, b_f, b_c, b_o, Cst, outH, outC);
}